// Round 11
// baseline (61.183 us; speedup 1.0000x reference)
//
#include <hip/hip_runtime.h>
#include <hip/hip_bf16.h>

#define NSEG 512
#define EPSF 1e-6f
#define MAIN_GRID 1024
#define MAIN_BLOCK 256
#define WAVES_PER_BLOCK 4

// d_ws layout:
//   [0, 16KB)          : gacc f64[2048] ([0..511]=count, [512..1023]=sum_x,
//                        [1024..1535]=sum_log, [1536..2047]=sum_log2)
//   [16KB, 16KB+8MB)   : per-block f32 partials, entry layout e = s*4+f

__global__ __launch_bounds__(1024) void zero_ws_kernel(double* __restrict__ g) {
    int i = blockIdx.x * blockDim.x + threadIdx.x;
    if (i < 4 * NSEG) g[i] = 0.0;
}

__global__ __launch_bounds__(MAIN_BLOCK) void seg_stats_kernel(const float4* __restrict__ x4,
                                                               const int4* __restrict__ i4,
                                                               float* __restrict__ parts,
                                                               double* __restrict__ gacc,
                                                               int n4, int use_parts) {
    // Per-wave histogram, tag packed into entry word0 = (tag:u16<<16)|count:u16
    // (R10). NEW: 8 items/thread/sweep (2 float4 groups) -> 8 concurrent
    // election chains, exact-division main loop with no bounds checks, and
    // TWO-slot sparse straggler rounds. No launch_bounds min-wave cap (R7's
    // spill trap): ~100 VGPR still sustains the LDS-bound 4 waves/SIMD.
    __shared__ float4 hist4[WAVES_PER_BLOCK][NSEG];  // 32 KB

    const int wave = threadIdx.x >> 6;
    const int lane = threadIdx.x & 63;
    float4* h = hist4[wave];
    unsigned short* tagp = (unsigned short*)h;  // tag of entry s = shorts[s*8+1]

    for (int i = threadIdx.x; i < WAVES_PER_BLOCK * NSEG; i += MAIN_BLOCK)
        ((float4*)hist4)[i] = make_float4(0.f, 0.f, 0.f, 0.f);
    __syncthreads();

    const int stride = gridDim.x * blockDim.x;
    const int base = blockIdx.x * blockDim.x + threadIdx.x;
    const int nfull = n4 / (2 * stride);  // = 8 for the benchmark shape

    if (nfull > 0) {
        float4 xa = x4[base], xb = x4[base + stride];
        int4 ia = i4[base], ib = i4[base + stride];
        for (int t = 0;; ++t) {
            bool more = (t + 1) < nfull;  // wave-uniform
            float4 xa_n, xb_n;
            int4 ia_n, ib_n;
            if (more) {
                int p = base + (t + 1) * 2 * stride;
                xa_n = x4[p];
                ia_n = i4[p];
                xb_n = x4[p + stride];
                ib_n = i4[p + stride];
            }

            float v[8] = {xa.x, xa.y, xa.z, xa.w, xb.x, xb.y, xb.z, xb.w};
            int s[8] = {ia.x, ia.y, ia.z, ia.w, ib.x, ib.y, ib.z, ib.w};
            float lx[8];
#pragma unroll
            for (int k = 0; k < 8; ++k) lx[k] = __logf(fabsf(v[k]) + EPSF);

            // ---- round 1: 8 tag writes + 8 speculative b128 reads ----
#pragma unroll
            for (int k = 0; k < 8; ++k)
                tagp[(s[k] << 3) + 1] = (unsigned short)(((k << 6) | lane) + 1);
            __asm__ volatile("" ::: "memory");
            float4 hv[8];
#pragma unroll
            for (int k = 0; k < 8; ++k) hv[k] = h[s[k]];
            __asm__ volatile("" ::: "memory");
            unsigned pendA = 0, pendB = 0;
#pragma unroll
            for (int k = 0; k < 8; ++k) {
                unsigned w0 = __float_as_uint(hv[k].x);
                if ((w0 >> 16) == (unsigned)(((k << 6) | lane) + 1)) {
                    h[s[k]] = make_float4(__uint_as_float((w0 & 0xFFFFu) + 1u),
                                          hv[k].y + v[k], hv[k].z + lx[k],
                                          hv[k].w + lx[k] * lx[k]);
                } else if (k < 4) {
                    pendA |= 1u << k;
                } else {
                    pendB |= 1u << (k - 4);
                }
            }

            // ---- sparse rounds: two compacted slots (A=items 0-3, B=4-7) ----
            while (__ballot((pendA | pendB) != 0)) {
                bool actA = pendA != 0, actB = pendB != 0;
                int sA = 0, sB = 0;
                float vA = 0.f, lA = 0.f, vB = 0.f, lB = 0.f;
                if (actA) {
                    int kA = __ffs(pendA) - 1;
                    sA = (kA == 0) ? s[0] : (kA == 1) ? s[1] : (kA == 2) ? s[2] : s[3];
                    vA = (kA == 0) ? v[0] : (kA == 1) ? v[1] : (kA == 2) ? v[2] : v[3];
                    lA = (kA == 0) ? lx[0] : (kA == 1) ? lx[1] : (kA == 2) ? lx[2] : lx[3];
                    tagp[(sA << 3) + 1] = (unsigned short)(lane + 1);
                }
                if (actB) {
                    int kB = __ffs(pendB) - 1;
                    sB = (kB == 0) ? s[4] : (kB == 1) ? s[5] : (kB == 2) ? s[6] : s[7];
                    vB = (kB == 0) ? v[4] : (kB == 1) ? v[5] : (kB == 2) ? v[6] : v[7];
                    lB = (kB == 0) ? lx[4] : (kB == 1) ? lx[5] : (kB == 2) ? lx[6] : lx[7];
                    tagp[(sB << 3) + 1] = (unsigned short)(lane + 65);
                }
                __asm__ volatile("" ::: "memory");
                float4 hA = make_float4(0.f, 0.f, 0.f, 0.f);
                float4 hB = make_float4(0.f, 0.f, 0.f, 0.f);
                if (actA) hA = h[sA];
                if (actB) hB = h[sB];
                __asm__ volatile("" ::: "memory");
                if (actA) {
                    unsigned w0 = __float_as_uint(hA.x);
                    if ((w0 >> 16) == (unsigned)(lane + 1)) {
                        h[sA] = make_float4(__uint_as_float((w0 & 0xFFFFu) + 1u),
                                            hA.y + vA, hA.z + lA, hA.w + lA * lA);
                        pendA &= pendA - 1;
                    }
                }
                if (actB) {
                    unsigned w0 = __float_as_uint(hB.x);
                    if ((w0 >> 16) == (unsigned)(lane + 65)) {
                        h[sB] = make_float4(__uint_as_float((w0 & 0xFFFFu) + 1u),
                                            hB.y + vB, hB.z + lB, hB.w + lB * lB);
                        pendB &= pendB - 1;
                    }
                }
            }

            if (!more) break;
            xa = xa_n;
            ia = ia_n;
            xb = xb_n;
            ib = ib_n;
        }
    }

    // ---- generic tail (empty for the benchmark shape) ----
    for (int i = base + nfull * 2 * stride; i < n4; i += stride) {
        float4 xv = x4[i];
        int4 iv = i4[i];
        float v[4] = {xv.x, xv.y, xv.z, xv.w};
        int s[4] = {iv.x, iv.y, iv.z, iv.w};
        float lx[4];
#pragma unroll
        for (int c = 0; c < 4; ++c) lx[c] = __logf(fabsf(v[c]) + EPSF);
        unsigned pend = 0xFu;
        while (__ballot(pend != 0)) {
            bool act = pend != 0;
            int s0 = 0;
            float v0 = 0.f, l0 = 0.f;
            if (act) {
                int k = __ffs(pend) - 1;
                s0 = (k == 0) ? s[0] : (k == 1) ? s[1] : (k == 2) ? s[2] : s[3];
                v0 = (k == 0) ? v[0] : (k == 1) ? v[1] : (k == 2) ? v[2] : v[3];
                l0 = (k == 0) ? lx[0] : (k == 1) ? lx[1] : (k == 2) ? lx[2] : lx[3];
                tagp[(s0 << 3) + 1] = (unsigned short)(lane + 1);
            }
            __asm__ volatile("" ::: "memory");
            float4 h0 = make_float4(0.f, 0.f, 0.f, 0.f);
            if (act) h0 = h[s0];
            __asm__ volatile("" ::: "memory");
            if (act) {
                unsigned w0 = __float_as_uint(h0.x);
                if ((w0 >> 16) == (unsigned)(lane + 1)) {
                    h[s0] = make_float4(__uint_as_float((w0 & 0xFFFFu) + 1u),
                                        h0.y + v0, h0.z + l0, h0.w + l0 * l0);
                    pend &= pend - 1;
                }
            }
        }
    }
    __syncthreads();

    // Combine the 4 wave copies; flush per block (float4 = entry layout s*4+f).
    for (int sg = threadIdx.x; sg < NSEG; sg += MAIN_BLOCK) {
        float4 a = hist4[0][sg];
        float4 b = hist4[1][sg];
        float4 cc = hist4[2][sg];
        float4 d = hist4[3][sg];
        unsigned cnt = (__float_as_uint(a.x) & 0xFFFFu) + (__float_as_uint(b.x) & 0xFFFFu) +
                       (__float_as_uint(cc.x) & 0xFFFFu) + (__float_as_uint(d.x) & 0xFFFFu);
        float4 t = make_float4((float)cnt, a.y + b.y + cc.y + d.y,
                               a.z + b.z + cc.z + d.z, a.w + b.w + cc.w + d.w);
        if (use_parts) {
            *(float4*)(parts + (size_t)blockIdx.x * (NSEG * 4) + (sg << 2)) = t;
        } else {
            if (t.x != 0.0f) unsafeAtomicAdd(&gacc[0 * NSEG + sg], (double)t.x);
            if (t.y != 0.0f) unsafeAtomicAdd(&gacc[1 * NSEG + sg], (double)t.y);
            if (t.z != 0.0f) unsafeAtomicAdd(&gacc[2 * NSEG + sg], (double)t.z);
            if (t.w != 0.0f) unsafeAtomicAdd(&gacc[3 * NSEG + sg], (double)t.w);
        }
    }
}

#define RP_CHUNKS 16  // 1024 partial blocks / 64 per chunk
__global__ __launch_bounds__(256) void reduce_partials_kernel(const float* __restrict__ parts,
                                                              double* __restrict__ gacc) {
    int eg = blockIdx.x & 7;
    int bc = blockIdx.x >> 3;
    int e = eg * 256 + threadIdx.x;  // 0..2047, entry layout s*4+f
    int b0 = bc * (MAIN_GRID / RP_CHUNKS);
    double acc = 0.0;
    for (int b = 0; b < MAIN_GRID / RP_CHUNKS; ++b)
        acc += (double)parts[(size_t)(b0 + b) * (NSEG * 4) + e];
    unsafeAtomicAdd(&gacc[(e & 3) * NSEG + (e >> 2)], acc);
}

__global__ __launch_bounds__(512) void finalize_kernel(const double* __restrict__ gacc,
                                                       const float* __restrict__ tmean,
                                                       const float* __restrict__ tstd,
                                                       float* __restrict__ out) {
    int s = threadIdx.x;  // 512 threads, one per segment
    double cnt = gacc[s];
    double c = cnt > 1.0 ? cnt : 1.0;
    double mean_w = gacc[NSEG + s] / c;
    double mean_log = gacc[2 * NSEG + s] / c;
    double var = gacc[3 * NSEG + s] / c - mean_log * mean_log;
    if (var < 0.0) var = 0.0;
    double std_w = sqrt(var + 1e-6);
    double dm = mean_w - (double)tmean[s];
    double dsd = std_w - (double)tstd[s];
    double term = 0.5 * dm * dm + 0.5 * dsd * dsd;

#pragma unroll
    for (int off = 32; off > 0; off >>= 1) term += __shfl_down(term, off, 64);

    __shared__ double part[8];
    int wid = threadIdx.x >> 6;
    if ((threadIdx.x & 63) == 0) part[wid] = term;
    __syncthreads();
    if (threadIdx.x == 0) {
        double t = 0.0;
#pragma unroll
        for (int i = 0; i < 8; ++i) t += part[i];
        out[0] = (float)((t / (double)NSEG) * 0.01);
    }
}

extern "C" void kernel_launch(void* const* d_in, const int* in_sizes, int n_in,
                              void* d_out, int out_size, void* d_ws, size_t ws_size,
                              hipStream_t stream) {
    const float* x = (const float*)d_in[0];
    const int* idx = (const int*)d_in[1];
    const float* tmean = (const float*)d_in[2];
    const float* tstd = (const float*)d_in[3];
    float* out = (float*)d_out;

    double* gacc = (double*)d_ws;
    float* parts = (float*)((char*)d_ws + 4 * NSEG * sizeof(double));
    size_t need = 4 * NSEG * sizeof(double) + (size_t)MAIN_GRID * NSEG * 4 * sizeof(float);
    int use_parts = (ws_size >= need) ? 1 : 0;

    int n = in_sizes[0];
    int n4 = n / 4;  // N_EDGES = 16777216, divisible by 4

    zero_ws_kernel<<<2, 1024, 0, stream>>>(gacc);
    seg_stats_kernel<<<MAIN_GRID, MAIN_BLOCK, 0, stream>>>((const float4*)x, (const int4*)idx,
                                                           parts, gacc, n4, use_parts);
    if (use_parts)
        reduce_partials_kernel<<<8 * RP_CHUNKS, 256, 0, stream>>>(parts, gacc);
    finalize_kernel<<<1, 512, 0, stream>>>(gacc, tmean, tstd, out);
}